// Round 2
// baseline (1761.200 us; speedup 1.0000x reference)
//
#include <hip/hip_runtime.h>
#include <hip/hip_bf16.h>

constexpr int NPOINTS = 2 * 16384;        // B*N
constexpr int NSAMP   = NPOINTS * 16;     // B*N*K

// ---------------------------------------------------------------- GEMM + stats
// y = X @ W (both f32), per-channel sum/sumsq via f64 atomics. 64 rows/block.
__global__ __launch_bounds__(128) void k_gemm_bn1(
    const float* __restrict__ X, const float* __restrict__ W,
    float* __restrict__ Y, double* __restrict__ dsum, double* __restrict__ dsq)
{
    __shared__ float wl[128 * 128];
    __shared__ float xrow[128];
    const int tid = threadIdx.x;
    for (int i = tid; i < 128 * 128; i += 128) wl[i] = W[i];
    __syncthreads();
    double ls = 0.0, lq = 0.0;
    const int r0 = blockIdx.x * 64;
    for (int r = r0; r < r0 + 64; ++r) {
        xrow[tid] = X[r * 128 + tid];
        __syncthreads();
        float acc = 0.f;
        #pragma unroll 16
        for (int j = 0; j < 128; ++j) acc = fmaf(xrow[j], wl[j * 128 + tid], acc);
        Y[r * 128 + tid] = acc;
        ls += acc; lq += (double)acc * acc;
        __syncthreads();
    }
    atomicAdd(&dsum[tid], ls);
    atomicAdd(&dsq[tid], lq);
}

// finalize BN: scale = g*rsqrt(var+eps), shift = b - mean*scale
__global__ void k_finalize(const double* __restrict__ sum, const double* __restrict__ sq,
                           const float* __restrict__ g, const float* __restrict__ b,
                           float* __restrict__ scale, float* __restrict__ shift, int nch, double cnt)
{
    int c = threadIdx.x;
    if (c < nch) {
        double m = sum[c] / cnt;
        double v = sq[c] / cnt - m * m;
        double s = (double)g[c] / sqrt(v + 1e-5);
        scale[c] = (float)s;
        shift[c] = (float)((double)b[c] - m * s);
    }
}

// out = relu(bn(Y)) @ W + bias   (generic linear used for q/k/v projections)
__global__ __launch_bounds__(128) void k_linear(
    const float* __restrict__ Y, const float* __restrict__ sc, const float* __restrict__ sh,
    const float* __restrict__ W, const float* __restrict__ Bias, float* __restrict__ Out)
{
    __shared__ float wl[128 * 128];
    __shared__ float frow[128];
    const int tid = threadIdx.x;
    for (int i = tid; i < 128 * 128; i += 128) wl[i] = W[i];
    const float a = sc[tid], b = sh[tid];
    const float bias = Bias[tid];
    __syncthreads();
    const int r0 = blockIdx.x * 64;
    for (int r = r0; r < r0 + 64; ++r) {
        frow[tid] = fmaxf(fmaf(a, Y[r * 128 + tid], b), 0.f);
        __syncthreads();
        float acc = bias;
        #pragma unroll 16
        for (int j = 0; j < 128; ++j) acc = fmaf(frow[j], wl[j * 128 + tid], acc);
        Out[r * 128 + tid] = acc;
        __syncthreads();
    }
}

// stats of h = rel @ fd_w1 + fd_b1 over (B,N,K), 3 channels
__global__ __launch_bounds__(256) void k_fd_stats(
    const float* __restrict__ xyz, const int* __restrict__ knn,
    const float* __restrict__ fdw1, const float* __restrict__ fdb1,
    double* __restrict__ dsum, double* __restrict__ dsq)
{
    float wd[9], bd[3];
    #pragma unroll
    for (int i = 0; i < 9; ++i) wd[i] = fdw1[i];
    #pragma unroll
    for (int j = 0; j < 3; ++j) bd[j] = fdb1[j];
    double ls[3] = {0, 0, 0}, lq[3] = {0, 0, 0};
    for (int s = blockIdx.x * blockDim.x + threadIdx.x; s < NSAMP; s += gridDim.x * blockDim.x) {
        int p = s >> 4;
        int b = p >> 14, n = p & 16383;
        int idx = knn[s];
        const float* pa = xyz + (b * 16384 + n) * 3;
        const float* pb = xyz + (b * 16384 + idx) * 3;
        float r0 = pa[0] - pb[0], r1 = pa[1] - pb[1], r2 = pa[2] - pb[2];
        #pragma unroll
        for (int j = 0; j < 3; ++j) {
            float h = r0 * wd[j] + r1 * wd[3 + j] + r2 * wd[6 + j] + bd[j];
            ls[j] += h; lq[j] += (double)h * h;
        }
    }
    #pragma unroll
    for (int j = 0; j < 3; ++j) {
        double v = ls[j];
        for (int o = 32; o; o >>= 1) v += __shfl_down(v, o);
        if ((threadIdx.x & 63) == 0) atomicAdd(&dsum[j], v);
        v = lq[j];
        for (int o = 32; o; o >>= 1) v += __shfl_down(v, o);
        if ((threadIdx.x & 63) == 0) atomicAdd(&dsq[j], v);
    }
}

// stats of attn0 = q - k_gather + pos_enc over (B,N,K), 128 channels
__global__ __launch_bounds__(128) void k_attn1_stats(
    const float* __restrict__ Q, const float* __restrict__ Kb,
    const float* __restrict__ xyz, const int* __restrict__ knn,
    const float* __restrict__ fdw1, const float* __restrict__ fdb1,
    const float* __restrict__ fds, const float* __restrict__ fdh,
    const float* __restrict__ fdw2, const float* __restrict__ fdb2,
    double* __restrict__ dsum, double* __restrict__ dsq)
{
    __shared__ float w2l[384];
    __shared__ float pe3[16][3];
    __shared__ int idxs[16];
    const int tid = threadIdx.x;
    for (int i = tid; i < 384; i += 128) w2l[i] = fdw2[i];
    const float b2c = fdb2[tid];
    float wd[9], bd[3], fs3[3], fh3[3];
    #pragma unroll
    for (int i = 0; i < 9; ++i) wd[i] = fdw1[i];
    #pragma unroll
    for (int j = 0; j < 3; ++j) { bd[j] = fdb1[j]; fs3[j] = fds[j]; fh3[j] = fdh[j]; }
    __syncthreads();
    double ls = 0.0, lq = 0.0;
    for (int p = blockIdx.x; p < NPOINTS; p += gridDim.x) {
        const int b = p >> 14;
        if (tid < 16) {
            const int idx = knn[p * 16 + tid];
            idxs[tid] = idx;
            const int n = p & 16383;
            const float* pa = xyz + (b * 16384 + n) * 3;
            const float* pb = xyz + (b * 16384 + idx) * 3;
            float r0 = pa[0] - pb[0], r1 = pa[1] - pb[1], r2 = pa[2] - pb[2];
            #pragma unroll
            for (int j = 0; j < 3; ++j) {
                float h = r0 * wd[j] + r1 * wd[3 + j] + r2 * wd[6 + j] + bd[j];
                pe3[tid][j] = fmaxf(fmaf(fs3[j], h, fh3[j]), 0.f);
            }
        }
        __syncthreads();
        const float qc = Q[p * 128 + tid];
        #pragma unroll
        for (int kk = 0; kk < 16; ++kk) {
            float pec = fmaf(pe3[kk][0], w2l[tid],
                        fmaf(pe3[kk][1], w2l[128 + tid],
                        fmaf(pe3[kk][2], w2l[256 + tid], b2c)));
            float a0 = qc - Kb[(b * 16384 + idxs[kk]) * 128 + tid] + pec;
            ls += a0; lq += (double)a0 * a0;
        }
        __syncthreads();
    }
    atomicAdd(&dsum[tid], ls);
    atomicAdd(&dsq[tid], lq);
}

// stats of t = relu(bn(attn0)) @ fg_w1 + fg_b1 over (B,N,K), 16 channels
__global__ __launch_bounds__(128) void k_attn2_stats(
    const float* __restrict__ Q, const float* __restrict__ Kb,
    const float* __restrict__ xyz, const int* __restrict__ knn,
    const float* __restrict__ fdw1, const float* __restrict__ fdb1,
    const float* __restrict__ fds, const float* __restrict__ fdh,
    const float* __restrict__ fdw2, const float* __restrict__ fdb2,
    const float* __restrict__ g1s, const float* __restrict__ g1h,
    const float* __restrict__ fgw1, const float* __restrict__ fgb1,
    double* __restrict__ dsum, double* __restrict__ dsq)
{
    __shared__ float w2l[384];
    __shared__ float fgw1l[2048];
    __shared__ float pe3[16][3];
    __shared__ int idxs[16];
    __shared__ float s1[128];
    __shared__ float part[8][16];
    const int tid = threadIdx.x;
    const int a = tid & 15, pr = tid >> 4;
    for (int i = tid; i < 384; i += 128) w2l[i] = fdw2[i];
    for (int i = tid; i < 2048; i += 128) fgw1l[i] = fgw1[i];
    const float b2c = fdb2[tid];
    const float g1sc = g1s[tid], g1sh = g1h[tid];
    const float tb = (tid < 16) ? fgb1[tid] : 0.f;
    float wd[9], bd[3], fs3[3], fh3[3];
    #pragma unroll
    for (int i = 0; i < 9; ++i) wd[i] = fdw1[i];
    #pragma unroll
    for (int j = 0; j < 3; ++j) { bd[j] = fdb1[j]; fs3[j] = fds[j]; fh3[j] = fdh[j]; }
    __syncthreads();
    double ls = 0.0, lq = 0.0;
    for (int p = blockIdx.x; p < NPOINTS; p += gridDim.x) {
        const int b = p >> 14;
        if (tid < 16) {
            const int idx = knn[p * 16 + tid];
            idxs[tid] = idx;
            const int n = p & 16383;
            const float* pa = xyz + (b * 16384 + n) * 3;
            const float* pb = xyz + (b * 16384 + idx) * 3;
            float r0 = pa[0] - pb[0], r1 = pa[1] - pb[1], r2 = pa[2] - pb[2];
            #pragma unroll
            for (int j = 0; j < 3; ++j) {
                float h = r0 * wd[j] + r1 * wd[3 + j] + r2 * wd[6 + j] + bd[j];
                pe3[tid][j] = fmaxf(fmaf(fs3[j], h, fh3[j]), 0.f);
            }
        }
        __syncthreads();
        const float qc = Q[p * 128 + tid];
        for (int kk = 0; kk < 16; ++kk) {
            float pec = fmaf(pe3[kk][0], w2l[tid],
                        fmaf(pe3[kk][1], w2l[128 + tid],
                        fmaf(pe3[kk][2], w2l[256 + tid], b2c)));
            float a0 = qc - Kb[(b * 16384 + idxs[kk]) * 128 + tid] + pec;
            s1[tid] = fmaxf(fmaf(g1sc, a0, g1sh), 0.f);
            __syncthreads();
            float pp = 0.f;
            #pragma unroll
            for (int i = 0; i < 16; ++i) { int c = pr * 16 + i; pp = fmaf(s1[c], fgw1l[c * 16 + a], pp); }
            part[pr][a] = pp;
            __syncthreads();
            if (tid < 16) {
                float t = tb;
                #pragma unroll
                for (int i = 0; i < 8; ++i) t += part[i][tid];
                ls += t; lq += (double)t * t;
            }
            __syncthreads();
        }
    }
    if (tid < 16) { atomicAdd(&dsum[tid], ls); atomicAdd(&dsq[tid], lq); }
}

// full attention: logits -> softmax over k -> res = sum_k (v+pos_enc)*attn ; bn2 stats
__global__ __launch_bounds__(128) void k_attn_final(
    const float* __restrict__ Q, const float* __restrict__ Kb, const float* __restrict__ Vb,
    const float* __restrict__ xyz, const int* __restrict__ knn,
    const float* __restrict__ fdw1, const float* __restrict__ fdb1,
    const float* __restrict__ fds, const float* __restrict__ fdh,
    const float* __restrict__ fdw2, const float* __restrict__ fdb2,
    const float* __restrict__ g1s, const float* __restrict__ g1h,
    const float* __restrict__ fgw1, const float* __restrict__ fgb1,
    const float* __restrict__ g2s, const float* __restrict__ g2h,
    const float* __restrict__ fgw2, const float* __restrict__ fgb2,
    float* __restrict__ Res, double* __restrict__ dsum, double* __restrict__ dsq)
{
    __shared__ float w2l[384];
    __shared__ float fgw1l[2048];
    __shared__ float fgw2l[256];
    __shared__ float pe3[16][3];
    __shared__ int idxs[16];
    __shared__ float s1[128];
    __shared__ float part[8][16];
    __shared__ float t16[16];
    __shared__ float U[16][16];
    __shared__ float Wt[16][16];
    __shared__ float pe[16 * 128];
    const int tid = threadIdx.x;
    const int a = tid & 15, pr = tid >> 4;
    for (int i = tid; i < 384; i += 128) w2l[i] = fdw2[i];
    for (int i = tid; i < 2048; i += 128) fgw1l[i] = fgw1[i];
    for (int i = tid; i < 256; i += 128) fgw2l[i] = fgw2[i];
    const float b2c = fdb2[tid];
    const float g1sc = g1s[tid], g1sh = g1h[tid];
    float tb = 0.f, s2a = 0.f, s2h = 0.f, b2a = 0.f;
    if (tid < 16) { tb = fgb1[tid]; s2a = g2s[tid]; s2h = g2h[tid]; b2a = fgb2[tid]; }
    float wd[9], bd[3], fs3[3], fh3[3];
    #pragma unroll
    for (int i = 0; i < 9; ++i) wd[i] = fdw1[i];
    #pragma unroll
    for (int j = 0; j < 3; ++j) { bd[j] = fdb1[j]; fs3[j] = fds[j]; fh3[j] = fdh[j]; }
    __syncthreads();
    double ls = 0.0, lq = 0.0;
    for (int p = blockIdx.x; p < NPOINTS; p += gridDim.x) {
        const int b = p >> 14;
        if (tid < 16) {
            const int idx = knn[p * 16 + tid];
            idxs[tid] = idx;
            const int n = p & 16383;
            const float* pa = xyz + (b * 16384 + n) * 3;
            const float* pb = xyz + (b * 16384 + idx) * 3;
            float r0 = pa[0] - pb[0], r1 = pa[1] - pb[1], r2 = pa[2] - pb[2];
            #pragma unroll
            for (int j = 0; j < 3; ++j) {
                float h = r0 * wd[j] + r1 * wd[3 + j] + r2 * wd[6 + j] + bd[j];
                pe3[tid][j] = fmaxf(fmaf(fs3[j], h, fh3[j]), 0.f);
            }
        }
        __syncthreads();
        const float qc = Q[p * 128 + tid];
        for (int kk = 0; kk < 16; ++kk) {
            float pec = fmaf(pe3[kk][0], w2l[tid],
                        fmaf(pe3[kk][1], w2l[128 + tid],
                        fmaf(pe3[kk][2], w2l[256 + tid], b2c)));
            pe[kk * 128 + tid] = pec;
            float a0 = qc - Kb[(b * 16384 + idxs[kk]) * 128 + tid] + pec;
            s1[tid] = fmaxf(fmaf(g1sc, a0, g1sh), 0.f);
            __syncthreads();
            float pp = 0.f;
            #pragma unroll
            for (int i = 0; i < 16; ++i) { int c = pr * 16 + i; pp = fmaf(s1[c], fgw1l[c * 16 + a], pp); }
            part[pr][a] = pp;
            __syncthreads();
            if (tid < 16) {
                float t = tb;
                #pragma unroll
                for (int i = 0; i < 8; ++i) t += part[i][tid];
                t16[tid] = fmaxf(fmaf(s2a, t, s2h), 0.f);
            }
            __syncthreads();
            if (tid < 16) {
                float u = b2a;
                #pragma unroll
                for (int j = 0; j < 16; ++j) u = fmaf(t16[j], fgw2l[j * 16 + tid], u);
                U[kk][tid] = u;
            }
            __syncthreads();
        }
        if (tid < 16) {
            float m = -1e30f;
            #pragma unroll
            for (int kk = 0; kk < 16; ++kk) m = fmaxf(m, U[kk][tid]);
            float ss = 0.f;
            #pragma unroll
            for (int kk = 0; kk < 16; ++kk) { float e = expf(U[kk][tid] - m); Wt[kk][tid] = e; ss += e; }
            float inv = 1.f / ss;
            #pragma unroll
            for (int kk = 0; kk < 16; ++kk) Wt[kk][tid] *= inv;
        }
        __syncthreads();
        float rc = 0.f;
        #pragma unroll
        for (int kk = 0; kk < 16; ++kk)
            rc = fmaf(Vb[(b * 16384 + idxs[kk]) * 128 + tid] + pe[kk * 128 + tid], Wt[kk][a], rc);
        Res[p * 128 + tid] = rc;
        ls += rc; lq += (double)rc * rc;
        __syncthreads();
    }
    atomicAdd(&dsum[tid], ls);
    atomicAdd(&dsq[tid], lq);
}

// y3 = relu(bn2(res)) @ w3 ; bn3 stats
__global__ __launch_bounds__(128) void k_gemm3(
    const float* __restrict__ Rin, const float* __restrict__ sc, const float* __restrict__ sh,
    const float* __restrict__ W3, float* __restrict__ Y3,
    double* __restrict__ dsum, double* __restrict__ dsq)
{
    __shared__ float wl[128 * 128];
    __shared__ float frow[128];
    const int tid = threadIdx.x;
    for (int i = tid; i < 128 * 128; i += 128) wl[i] = W3[i];
    const float a = sc[tid], b = sh[tid];
    __syncthreads();
    double ls = 0.0, lq = 0.0;
    const int r0 = blockIdx.x * 64;
    for (int r = r0; r < r0 + 64; ++r) {
        frow[tid] = fmaxf(fmaf(a, Rin[r * 128 + tid], b), 0.f);
        __syncthreads();
        float acc = 0.f;
        #pragma unroll 16
        for (int j = 0; j < 128; ++j) acc = fmaf(frow[j], wl[j * 128 + tid], acc);
        Y3[r * 128 + tid] = acc;
        ls += acc; lq += (double)acc * acc;
        __syncthreads();
    }
    atomicAdd(&dsum[tid], ls);
    atomicAdd(&dsq[tid], lq);
}

// out = relu(bn3(y3) + identity)
__global__ void k_out(const float* __restrict__ Y3, const float* __restrict__ sc,
                      const float* __restrict__ sh, const float* __restrict__ feat,
                      float* __restrict__ out)
{
    const int total = NPOINTS * 128;
    for (int i = blockIdx.x * blockDim.x + threadIdx.x; i < total; i += gridDim.x * blockDim.x) {
        int c = i & 127;
        float v = fmaf(sc[c], Y3[i], sh[c]) + feat[i];
        out[i] = fmaxf(v, 0.f);
    }
}

__global__ void k_copy_f32(const float* __restrict__ s, float* __restrict__ d, int n)
{
    for (int i = blockIdx.x * blockDim.x + threadIdx.x; i < n; i += gridDim.x * blockDim.x) d[i] = s[i];
}

extern "C" void kernel_launch(void* const* d_in, const int* in_sizes, int n_in,
                              void* d_out, int out_size, void* d_ws, size_t ws_size,
                              hipStream_t stream)
{
    (void)in_sizes; (void)n_in; (void)out_size; (void)ws_size;
    const float* xyz   = (const float*)d_in[0];
    const float* feat  = (const float*)d_in[1];
    const int*   knn   = (const int*)d_in[2];
    const float* w1    = (const float*)d_in[3];
    const float* bn1g  = (const float*)d_in[4];
    const float* bn1b  = (const float*)d_in[5];
    const float* lqw   = (const float*)d_in[6];
    const float* lqb   = (const float*)d_in[7];
    const float* lkw   = (const float*)d_in[8];
    const float* lkb   = (const float*)d_in[9];
    const float* lvw   = (const float*)d_in[10];
    const float* lvb   = (const float*)d_in[11];
    const float* fdw1  = (const float*)d_in[12];
    const float* fdb1  = (const float*)d_in[13];
    const float* fdbng = (const float*)d_in[14];
    const float* fdbnb = (const float*)d_in[15];
    const float* fdw2  = (const float*)d_in[16];
    const float* fdb2  = (const float*)d_in[17];
    const float* g1g   = (const float*)d_in[18];
    const float* g1b   = (const float*)d_in[19];
    const float* fgw1  = (const float*)d_in[20];
    const float* fgb1  = (const float*)d_in[21];
    const float* g2g   = (const float*)d_in[22];
    const float* g2b   = (const float*)d_in[23];
    const float* fgw2  = (const float*)d_in[24];
    const float* fgb2  = (const float*)d_in[25];
    const float* bn2g  = (const float*)d_in[26];
    const float* bn2b  = (const float*)d_in[27];
    const float* w3    = (const float*)d_in[28];
    const float* bn3g  = (const float*)d_in[29];
    const float* bn3b  = (const float*)d_in[30];

    float* wsf  = (float*)d_ws;
    float* BUF0 = wsf;                    // y, later res
    float* BUFQ = wsf + 4194304;          // q, later y3
    float* BUFK = wsf + 2 * 4194304;
    float* BUFV = wsf + 3 * 4194304;
    double* ds  = (double*)(wsf + 4 * 4194304);
    float*  fs  = (float*)(ds + 1072);

    hipMemsetAsync(ds, 0, 1072 * sizeof(double), stream);

    // bn1 over feat@w1 (cnt 32768, 128ch)
    k_gemm_bn1<<<512, 128, 0, stream>>>(feat, w1, BUF0, ds + 0, ds + 128);
    k_finalize<<<1, 128, 0, stream>>>(ds + 0, ds + 128, bn1g, bn1b, fs + 0, fs + 128, 128, (double)NPOINTS);
    // q,k,v projections: f = relu(bn1(y)), {q,k,v} = f @ W + b
    k_linear<<<512, 128, 0, stream>>>(BUF0, fs + 0, fs + 128, lqw, lqb, BUFQ);
    k_linear<<<512, 128, 0, stream>>>(BUF0, fs + 0, fs + 128, lkw, lkb, BUFK);
    k_linear<<<512, 128, 0, stream>>>(BUF0, fs + 0, fs + 128, lvw, lvb, BUFV);
    // fd BN stats (cnt 524288, 3ch)
    k_fd_stats<<<128, 256, 0, stream>>>(xyz, knn, fdw1, fdb1, ds + 256, ds + 264);
    k_finalize<<<1, 128, 0, stream>>>(ds + 256, ds + 264, fdbng, fdbnb, fs + 256, fs + 264, 3, (double)NSAMP);
    // fg_bn1 stats (cnt 524288, 128ch)
    k_attn1_stats<<<512, 128, 0, stream>>>(BUFQ, BUFK, xyz, knn, fdw1, fdb1, fs + 256, fs + 264,
                                           fdw2, fdb2, ds + 272, ds + 400);
    k_finalize<<<1, 128, 0, stream>>>(ds + 272, ds + 400, g1g, g1b, fs + 272, fs + 400, 128, (double)NSAMP);
    // fg_bn2 stats (cnt 524288, 16ch)
    k_attn2_stats<<<512, 128, 0, stream>>>(BUFQ, BUFK, xyz, knn, fdw1, fdb1, fs + 256, fs + 264,
                                           fdw2, fdb2, fs + 272, fs + 400, fgw1, fgb1, ds + 528, ds + 544);
    k_finalize<<<1, 128, 0, stream>>>(ds + 528, ds + 544, g2g, g2b, fs + 528, fs + 544, 16, (double)NSAMP);
    // final attention -> res (BUF0), bn2 stats
    k_attn_final<<<1024, 128, 0, stream>>>(BUFQ, BUFK, BUFV, xyz, knn, fdw1, fdb1, fs + 256, fs + 264,
                                           fdw2, fdb2, fs + 272, fs + 400, fgw1, fgb1,
                                           fs + 528, fs + 544, fgw2, fgb2,
                                           BUF0, ds + 560, ds + 688);
    k_finalize<<<1, 128, 0, stream>>>(ds + 560, ds + 688, bn2g, bn2b, fs + 560, fs + 688, 128, (double)NPOINTS);
    // y3 = relu(bn2(res)) @ w3 -> BUFQ, bn3 stats
    k_gemm3<<<512, 128, 0, stream>>>(BUF0, fs + 560, fs + 688, w3, BUFQ, ds + 816, ds + 944);
    k_finalize<<<1, 128, 0, stream>>>(ds + 816, ds + 944, bn3g, bn3b, fs + 816, fs + 944, 128, (double)NPOINTS);
    // output
    float* outp = (float*)d_out;
    k_out<<<2048, 256, 0, stream>>>(BUFQ, fs + 816, fs + 944, feat, outp + 98304);
    k_copy_f32<<<192, 256, 0, stream>>>(xyz, outp, 98304);
}

// Round 3
// 667.665 us; speedup vs baseline: 2.6379x; 2.6379x over previous
//
#include <hip/hip_runtime.h>
#include <hip/hip_bf16.h>

constexpr int NPOINTS = 2 * 16384;        // B*N
constexpr int NSAMP   = NPOINTS * 16;     // B*N*K

// ---------------------------------------------------------------- GEMM + bn stats
// y = X @ W (f32). 512 threads = 4 rows per barrier round. Per-channel stats.
__global__ __launch_bounds__(512) void k_gemm_bn1(
    const float* __restrict__ X, const float* __restrict__ W,
    float* __restrict__ Y, double* __restrict__ dsum, double* __restrict__ dsq)
{
    __shared__ float wl[128 * 128];
    __shared__ float xr[4][128];
    __shared__ double rd[512];
    const int tid = threadIdx.x;
    const int h = tid >> 7, c = tid & 127;
    for (int i = tid; i < 128 * 128; i += 512) wl[i] = W[i];
    __syncthreads();
    double ls = 0.0, lq = 0.0;
    const int r0 = blockIdx.x * 64;
    for (int r = r0; r < r0 + 64; r += 4) {
        xr[h][c] = X[(r + h) * 128 + c];
        __syncthreads();
        float acc = 0.f;
        #pragma unroll 8
        for (int j = 0; j < 128; ++j) acc = fmaf(xr[h][j], wl[j * 128 + c], acc);
        Y[(r + h) * 128 + c] = acc;
        ls += acc; lq += (double)acc * acc;
        __syncthreads();
    }
    rd[tid] = ls; __syncthreads();
    double ts = (h == 0) ? (rd[c] + rd[128 + c] + rd[256 + c] + rd[384 + c]) : 0.0;
    __syncthreads();
    rd[tid] = lq; __syncthreads();
    if (h == 0) {
        double tq = rd[c] + rd[128 + c] + rd[256 + c] + rd[384 + c];
        atomicAdd(&dsum[c], ts);
        atomicAdd(&dsq[c], tq);
    }
}

// finalize BN: scale = g*rsqrt(var+eps), shift = b - mean*scale
__global__ void k_finalize(const double* __restrict__ sum, const double* __restrict__ sq,
                           const float* __restrict__ g, const float* __restrict__ b,
                           float* __restrict__ scale, float* __restrict__ shift, int nch, double cnt)
{
    int c = threadIdx.x;
    if (c < nch) {
        double m = sum[c] / cnt;
        double v = sq[c] / cnt - m * m;
        double s = (double)g[c] / sqrt(v + 1e-5);
        scale[c] = (float)s;
        shift[c] = (float)((double)b[c] - m * s);
    }
}

// out = relu(bn(Y)) @ W + bias
__global__ __launch_bounds__(512) void k_linear(
    const float* __restrict__ Y, const float* __restrict__ sc, const float* __restrict__ sh,
    const float* __restrict__ W, const float* __restrict__ Bias, float* __restrict__ Out)
{
    __shared__ float wl[128 * 128];
    __shared__ float xr[4][128];
    const int tid = threadIdx.x;
    const int h = tid >> 7, c = tid & 127;
    for (int i = tid; i < 128 * 128; i += 512) wl[i] = W[i];
    const float a = sc[c], b = sh[c];
    const float bias = Bias[c];
    __syncthreads();
    const int r0 = blockIdx.x * 64;
    for (int r = r0; r < r0 + 64; r += 4) {
        xr[h][c] = fmaxf(fmaf(a, Y[(r + h) * 128 + c], b), 0.f);
        __syncthreads();
        float acc = bias;
        #pragma unroll 8
        for (int j = 0; j < 128; ++j) acc = fmaf(xr[h][j], wl[j * 128 + c], acc);
        Out[(r + h) * 128 + c] = acc;
        __syncthreads();
    }
}

// stats of h = rel @ fd_w1 + fd_b1 over (B,N,K), 3 channels
__global__ __launch_bounds__(256) void k_fd_stats(
    const float* __restrict__ xyz, const int* __restrict__ knn,
    const float* __restrict__ fdw1, const float* __restrict__ fdb1,
    double* __restrict__ dsum, double* __restrict__ dsq)
{
    float wd[9], bd[3];
    #pragma unroll
    for (int i = 0; i < 9; ++i) wd[i] = fdw1[i];
    #pragma unroll
    for (int j = 0; j < 3; ++j) bd[j] = fdb1[j];
    double ls[3] = {0, 0, 0}, lq[3] = {0, 0, 0};
    for (int s = blockIdx.x * blockDim.x + threadIdx.x; s < NSAMP; s += gridDim.x * blockDim.x) {
        int p = s >> 4;
        int b = p >> 14, n = p & 16383;
        int idx = knn[s];
        const float* pa = xyz + (b * 16384 + n) * 3;
        const float* pb = xyz + (b * 16384 + idx) * 3;
        float r0 = pa[0] - pb[0], r1 = pa[1] - pb[1], r2 = pa[2] - pb[2];
        #pragma unroll
        for (int j = 0; j < 3; ++j) {
            float h = r0 * wd[j] + r1 * wd[3 + j] + r2 * wd[6 + j] + bd[j];
            ls[j] += h; lq[j] += (double)h * h;
        }
    }
    #pragma unroll
    for (int j = 0; j < 3; ++j) {
        double v = ls[j];
        for (int o = 32; o; o >>= 1) v += __shfl_down(v, o);
        if ((threadIdx.x & 63) == 0) atomicAdd(&dsum[j], v);
        v = lq[j];
        for (int o = 32; o; o >>= 1) v += __shfl_down(v, o);
        if ((threadIdx.x & 63) == 0) atomicAdd(&dsq[j], v);
    }
}

// stats of attn0 = q - k_gather + pos_enc over (B,N,K), 128 channels
__global__ __launch_bounds__(128) void k_attn1_stats(
    const float* __restrict__ Q, const float* __restrict__ Kb,
    const float* __restrict__ xyz, const int* __restrict__ knn,
    const float* __restrict__ fdw1, const float* __restrict__ fdb1,
    const float* __restrict__ fds, const float* __restrict__ fdh,
    const float* __restrict__ fdw2, const float* __restrict__ fdb2,
    double* __restrict__ dsum, double* __restrict__ dsq)
{
    __shared__ float pe3[16][3];
    __shared__ int idxs[16];
    const int tid = threadIdx.x;
    const float w0 = fdw2[tid], w1c = fdw2[128 + tid], w2c = fdw2[256 + tid], b2c = fdb2[tid];
    float wd[9], bd[3], fs3[3], fh3[3];
    #pragma unroll
    for (int i = 0; i < 9; ++i) wd[i] = fdw1[i];
    #pragma unroll
    for (int j = 0; j < 3; ++j) { bd[j] = fdb1[j]; fs3[j] = fds[j]; fh3[j] = fdh[j]; }
    double ls = 0.0, lq = 0.0;
    for (int p = blockIdx.x; p < NPOINTS; p += gridDim.x) {
        const int b = p >> 14;
        if (tid < 16) {
            const int idx = knn[p * 16 + tid];
            idxs[tid] = idx;
            const int n = p & 16383;
            const float* pa = xyz + (b * 16384 + n) * 3;
            const float* pb = xyz + (b * 16384 + idx) * 3;
            float r0 = pa[0] - pb[0], r1 = pa[1] - pb[1], r2 = pa[2] - pb[2];
            #pragma unroll
            for (int j = 0; j < 3; ++j) {
                float h = r0 * wd[j] + r1 * wd[3 + j] + r2 * wd[6 + j] + bd[j];
                pe3[tid][j] = fmaxf(fmaf(fs3[j], h, fh3[j]), 0.f);
            }
        }
        __syncthreads();
        const float qc = Q[p * 128 + tid];
        const float* kbase = Kb + (size_t)(b << 14) * 128;
        #pragma unroll
        for (int kk = 0; kk < 16; ++kk) {
            float kv = kbase[idxs[kk] * 128 + tid];
            float pec = fmaf(pe3[kk][0], w0, fmaf(pe3[kk][1], w1c, fmaf(pe3[kk][2], w2c, b2c)));
            float a0 = qc - kv + pec;
            ls += a0; lq += (double)a0 * a0;
        }
        __syncthreads();
    }
    atomicAdd(&dsum[tid], ls);
    atomicAdd(&dsq[tid], lq);
}

// stats of t = relu(bn(attn0)) @ fg_w1 + fg_b1 over (B,N,K), 16 channels
// parallel-kk layout: thread c builds s1[kk][c]; then (k,a) threads do the 16x16 matmul.
__global__ __launch_bounds__(128) void k_attn2_stats(
    const float* __restrict__ Q, const float* __restrict__ Kb,
    const float* __restrict__ xyz, const int* __restrict__ knn,
    const float* __restrict__ fdw1, const float* __restrict__ fdb1,
    const float* __restrict__ fds, const float* __restrict__ fdh,
    const float* __restrict__ fdw2, const float* __restrict__ fdb2,
    const float* __restrict__ g1s, const float* __restrict__ g1h,
    const float* __restrict__ fgw1, const float* __restrict__ fgb1,
    double* __restrict__ dsum, double* __restrict__ dsq)
{
    __shared__ float fgw1l[2048];
    __shared__ float s1[16 * 132];
    __shared__ float pe3[16][3];
    __shared__ int idxs[16];
    __shared__ double rd[128];
    const int tid = threadIdx.x;
    const int ka = tid & 15, kr = tid >> 4;
    for (int i = tid; i < 2048; i += 128) fgw1l[i] = fgw1[i];
    const float w0 = fdw2[tid], w1c = fdw2[128 + tid], w2c = fdw2[256 + tid], b2c = fdb2[tid];
    const float g1sc = g1s[tid], g1sh = g1h[tid];
    const float tb = fgb1[ka];
    float wd[9], bd[3], fs3[3], fh3[3];
    #pragma unroll
    for (int i = 0; i < 9; ++i) wd[i] = fdw1[i];
    #pragma unroll
    for (int j = 0; j < 3; ++j) { bd[j] = fdb1[j]; fs3[j] = fds[j]; fh3[j] = fdh[j]; }
    __syncthreads();
    double ls = 0.0, lq = 0.0;
    for (int p = blockIdx.x; p < NPOINTS; p += gridDim.x) {
        const int b = p >> 14;
        if (tid < 16) {
            const int idx = knn[p * 16 + tid];
            idxs[tid] = idx;
            const int n = p & 16383;
            const float* pa = xyz + (b * 16384 + n) * 3;
            const float* pb = xyz + (b * 16384 + idx) * 3;
            float r0 = pa[0] - pb[0], r1 = pa[1] - pb[1], r2 = pa[2] - pb[2];
            #pragma unroll
            for (int j = 0; j < 3; ++j) {
                float h = r0 * wd[j] + r1 * wd[3 + j] + r2 * wd[6 + j] + bd[j];
                pe3[tid][j] = fmaxf(fmaf(fs3[j], h, fh3[j]), 0.f);
            }
        }
        __syncthreads();
        const float qc = Q[p * 128 + tid];
        const float* kbase = Kb + (size_t)(b << 14) * 128;
        #pragma unroll
        for (int kk = 0; kk < 16; ++kk) {
            float kv = kbase[idxs[kk] * 128 + tid];
            float pec = fmaf(pe3[kk][0], w0, fmaf(pe3[kk][1], w1c, fmaf(pe3[kk][2], w2c, b2c)));
            float a0 = qc - kv + pec;
            s1[kk * 132 + tid] = fmaxf(fmaf(g1sc, a0, g1sh), 0.f);
        }
        __syncthreads();
        float t0 = tb, t1 = tb;
        #pragma unroll 8
        for (int c = 0; c < 128; ++c) {
            float w = fgw1l[c * 16 + ka];
            t0 = fmaf(s1[kr * 132 + c], w, t0);
            t1 = fmaf(s1[(kr + 8) * 132 + c], w, t1);
        }
        ls += (double)t0 + (double)t1;
        lq += (double)t0 * t0 + (double)t1 * t1;
        __syncthreads();
    }
    rd[tid] = ls; __syncthreads();
    double ts = 0.0;
    if (kr == 0) { for (int i = 0; i < 8; ++i) ts += rd[ka + 16 * i]; }
    __syncthreads();
    rd[tid] = lq; __syncthreads();
    if (kr == 0) {
        double tq = 0.0;
        for (int i = 0; i < 8; ++i) tq += rd[ka + 16 * i];
        atomicAdd(&dsum[ka], ts);
        atomicAdd(&dsq[ka], tq);
    }
}

// full attention: logits -> softmax over k -> res ; bn2 stats. Parallel-kk layout.
__global__ __launch_bounds__(128) void k_attn_final(
    const float* __restrict__ Q, const float* __restrict__ Kb, const float* __restrict__ Vb,
    const float* __restrict__ xyz, const int* __restrict__ knn,
    const float* __restrict__ fdw1, const float* __restrict__ fdb1,
    const float* __restrict__ fds, const float* __restrict__ fdh,
    const float* __restrict__ fdw2, const float* __restrict__ fdb2,
    const float* __restrict__ g1s, const float* __restrict__ g1h,
    const float* __restrict__ fgw1, const float* __restrict__ fgb1,
    const float* __restrict__ g2s, const float* __restrict__ g2h,
    const float* __restrict__ fgw2, const float* __restrict__ fgb2,
    float* __restrict__ Res, double* __restrict__ dsum, double* __restrict__ dsq)
{
    __shared__ float fgw1l[2048];
    __shared__ float fgw2l[256];
    __shared__ float s1[16 * 132];
    __shared__ float t2l[16 * 17];
    __shared__ float ul[16 * 17];     // logits, then softmax weights in place
    __shared__ float pe3[16][3];
    __shared__ int idxs[16];
    const int tid = threadIdx.x;
    const int ka = tid & 15, kr = tid >> 4;
    for (int i = tid; i < 2048; i += 128) fgw1l[i] = fgw1[i];
    for (int i = tid; i < 256; i += 128) fgw2l[i] = fgw2[i];
    const float w0 = fdw2[tid], w1c = fdw2[128 + tid], w2c = fdw2[256 + tid], b2c = fdb2[tid];
    const float g1sc = g1s[tid], g1sh = g1h[tid];
    const float tb = fgb1[ka];
    const float s2a = g2s[ka], s2h = g2h[ka], b2a = fgb2[ka];
    float wd[9], bd[3], fs3[3], fh3[3];
    #pragma unroll
    for (int i = 0; i < 9; ++i) wd[i] = fdw1[i];
    #pragma unroll
    for (int j = 0; j < 3; ++j) { bd[j] = fdb1[j]; fs3[j] = fds[j]; fh3[j] = fdh[j]; }
    __syncthreads();
    double ls = 0.0, lq = 0.0;
    for (int p = blockIdx.x; p < NPOINTS; p += gridDim.x) {
        const int b = p >> 14;
        if (tid < 16) {
            const int idx = knn[p * 16 + tid];
            idxs[tid] = idx;
            const int n = p & 16383;
            const float* pa = xyz + (b * 16384 + n) * 3;
            const float* pb = xyz + (b * 16384 + idx) * 3;
            float r0 = pa[0] - pb[0], r1 = pa[1] - pb[1], r2 = pa[2] - pb[2];
            #pragma unroll
            for (int j = 0; j < 3; ++j) {
                float h = r0 * wd[j] + r1 * wd[3 + j] + r2 * wd[6 + j] + bd[j];
                pe3[tid][j] = fmaxf(fmaf(fs3[j], h, fh3[j]), 0.f);
            }
        }
        __syncthreads();
        // s1[kk][c] for all kk
        const float qc = Q[p * 128 + tid];
        const float* kbase = Kb + (size_t)(b << 14) * 128;
        #pragma unroll
        for (int kk = 0; kk < 16; ++kk) {
            float kv = kbase[idxs[kk] * 128 + tid];
            float pec = fmaf(pe3[kk][0], w0, fmaf(pe3[kk][1], w1c, fmaf(pe3[kk][2], w2c, b2c)));
            float a0 = qc - kv + pec;
            s1[kk * 132 + tid] = fmaxf(fmaf(g1sc, a0, g1sh), 0.f);
        }
        __syncthreads();
        // stage1: t = s1 @ fgw1 + fgb1 ; t2 = relu(bn(t))
        {
            float t0 = tb, t1 = tb;
            #pragma unroll 8
            for (int c = 0; c < 128; ++c) {
                float w = fgw1l[c * 16 + ka];
                t0 = fmaf(s1[kr * 132 + c], w, t0);
                t1 = fmaf(s1[(kr + 8) * 132 + c], w, t1);
            }
            t2l[kr * 17 + ka] = fmaxf(fmaf(s2a, t0, s2h), 0.f);
            t2l[(kr + 8) * 17 + ka] = fmaxf(fmaf(s2a, t1, s2h), 0.f);
        }
        __syncthreads();
        // stage2: u = t2 @ fgw2 + fgb2
        {
            float u0 = b2a, u1 = b2a;
            #pragma unroll
            for (int j = 0; j < 16; ++j) {
                float w = fgw2l[j * 16 + ka];
                u0 = fmaf(t2l[kr * 17 + j], w, u0);
                u1 = fmaf(t2l[(kr + 8) * 17 + j], w, u1);
            }
            ul[kr * 17 + ka] = u0;
            ul[(kr + 8) * 17 + ka] = u1;
        }
        __syncthreads();
        // softmax over k per column a (in place)
        if (tid < 16) {
            float m = -1e30f;
            #pragma unroll
            for (int kk = 0; kk < 16; ++kk) m = fmaxf(m, ul[kk * 17 + tid]);
            float ss = 0.f;
            #pragma unroll
            for (int kk = 0; kk < 16; ++kk) { float e = expf(ul[kk * 17 + tid] - m); ul[kk * 17 + tid] = e; ss += e; }
            float inv = 1.f / ss;
            #pragma unroll
            for (int kk = 0; kk < 16; ++kk) ul[kk * 17 + tid] *= inv;
        }
        __syncthreads();
        // PV: res[c] = sum_k (V[idx_k][c] + pe[k][c]) * w[k][c&15]
        {
            const float* vbase = Vb + (size_t)(b << 14) * 128;
            float rc = 0.f;
            #pragma unroll
            for (int kk = 0; kk < 16; ++kk) {
                float vv = vbase[idxs[kk] * 128 + tid];
                float pec = fmaf(pe3[kk][0], w0, fmaf(pe3[kk][1], w1c, fmaf(pe3[kk][2], w2c, b2c)));
                rc = fmaf(vv + pec, ul[kk * 17 + ka], rc);
            }
            Res[p * 128 + tid] = rc;
            ls += rc; lq += (double)rc * rc;
        }
        __syncthreads();
    }
    atomicAdd(&dsum[tid], ls);
    atomicAdd(&dsq[tid], lq);
}

// y3 = relu(bn2(res)) @ w3 ; bn3 stats
__global__ __launch_bounds__(512) void k_gemm3(
    const float* __restrict__ Rin, const float* __restrict__ sc, const float* __restrict__ sh,
    const float* __restrict__ W3, float* __restrict__ Y3,
    double* __restrict__ dsum, double* __restrict__ dsq)
{
    __shared__ float wl[128 * 128];
    __shared__ float xr[4][128];
    __shared__ double rd[512];
    const int tid = threadIdx.x;
    const int h = tid >> 7, c = tid & 127;
    for (int i = tid; i < 128 * 128; i += 512) wl[i] = W3[i];
    const float a = sc[c], b = sh[c];
    __syncthreads();
    double ls = 0.0, lq = 0.0;
    const int r0 = blockIdx.x * 64;
    for (int r = r0; r < r0 + 64; r += 4) {
        xr[h][c] = fmaxf(fmaf(a, Rin[(r + h) * 128 + c], b), 0.f);
        __syncthreads();
        float acc = 0.f;
        #pragma unroll 8
        for (int j = 0; j < 128; ++j) acc = fmaf(xr[h][j], wl[j * 128 + c], acc);
        Y3[(r + h) * 128 + c] = acc;
        ls += acc; lq += (double)acc * acc;
        __syncthreads();
    }
    rd[tid] = ls; __syncthreads();
    double ts = (h == 0) ? (rd[c] + rd[128 + c] + rd[256 + c] + rd[384 + c]) : 0.0;
    __syncthreads();
    rd[tid] = lq; __syncthreads();
    if (h == 0) {
        double tq = rd[c] + rd[128 + c] + rd[256 + c] + rd[384 + c];
        atomicAdd(&dsum[c], ts);
        atomicAdd(&dsq[c], tq);
    }
}

// out = relu(bn3(y3) + identity)
__global__ void k_out(const float* __restrict__ Y3, const float* __restrict__ sc,
                      const float* __restrict__ sh, const float* __restrict__ feat,
                      float* __restrict__ out)
{
    const int total = NPOINTS * 128;
    for (int i = blockIdx.x * blockDim.x + threadIdx.x; i < total; i += gridDim.x * blockDim.x) {
        int c = i & 127;
        float v = fmaf(sc[c], Y3[i], sh[c]) + feat[i];
        out[i] = fmaxf(v, 0.f);
    }
}

__global__ void k_copy_f32(const float* __restrict__ s, float* __restrict__ d, int n)
{
    for (int i = blockIdx.x * blockDim.x + threadIdx.x; i < n; i += gridDim.x * blockDim.x) d[i] = s[i];
}

extern "C" void kernel_launch(void* const* d_in, const int* in_sizes, int n_in,
                              void* d_out, int out_size, void* d_ws, size_t ws_size,
                              hipStream_t stream)
{
    (void)in_sizes; (void)n_in; (void)out_size; (void)ws_size;
    const float* xyz   = (const float*)d_in[0];
    const float* feat  = (const float*)d_in[1];
    const int*   knn   = (const int*)d_in[2];
    const float* w1    = (const float*)d_in[3];
    const float* bn1g  = (const float*)d_in[4];
    const float* bn1b  = (const float*)d_in[5];
    const float* lqw   = (const float*)d_in[6];
    const float* lqb   = (const float*)d_in[7];
    const float* lkw   = (const float*)d_in[8];
    const float* lkb   = (const float*)d_in[9];
    const float* lvw   = (const float*)d_in[10];
    const float* lvb   = (const float*)d_in[11];
    const float* fdw1  = (const float*)d_in[12];
    const float* fdb1  = (const float*)d_in[13];
    const float* fdbng = (const float*)d_in[14];
    const float* fdbnb = (const float*)d_in[15];
    const float* fdw2  = (const float*)d_in[16];
    const float* fdb2  = (const float*)d_in[17];
    const float* g1g   = (const float*)d_in[18];
    const float* g1b   = (const float*)d_in[19];
    const float* fgw1  = (const float*)d_in[20];
    const float* fgb1  = (const float*)d_in[21];
    const float* g2g   = (const float*)d_in[22];
    const float* g2b   = (const float*)d_in[23];
    const float* fgw2  = (const float*)d_in[24];
    const float* fgb2  = (const float*)d_in[25];
    const float* bn2g  = (const float*)d_in[26];
    const float* bn2b  = (const float*)d_in[27];
    const float* w3    = (const float*)d_in[28];
    const float* bn3g  = (const float*)d_in[29];
    const float* bn3b  = (const float*)d_in[30];

    float* wsf  = (float*)d_ws;
    float* BUF0 = wsf;                    // y, later res
    float* BUFQ = wsf + 4194304;          // q, later y3
    float* BUFK = wsf + 2 * 4194304;
    float* BUFV = wsf + 3 * 4194304;
    double* ds  = (double*)(wsf + 4 * 4194304);
    float*  fs  = (float*)(ds + 1072);

    hipMemsetAsync(ds, 0, 1072 * sizeof(double), stream);

    // bn1 over feat@w1 (cnt 32768, 128ch)
    k_gemm_bn1<<<512, 512, 0, stream>>>(feat, w1, BUF0, ds + 0, ds + 128);
    k_finalize<<<1, 128, 0, stream>>>(ds + 0, ds + 128, bn1g, bn1b, fs + 0, fs + 128, 128, (double)NPOINTS);
    // q,k,v projections: f = relu(bn1(y)), {q,k,v} = f @ W + b
    k_linear<<<512, 512, 0, stream>>>(BUF0, fs + 0, fs + 128, lqw, lqb, BUFQ);
    k_linear<<<512, 512, 0, stream>>>(BUF0, fs + 0, fs + 128, lkw, lkb, BUFK);
    k_linear<<<512, 512, 0, stream>>>(BUF0, fs + 0, fs + 128, lvw, lvb, BUFV);
    // fd BN stats (cnt 524288, 3ch)
    k_fd_stats<<<256, 256, 0, stream>>>(xyz, knn, fdw1, fdb1, ds + 256, ds + 264);
    k_finalize<<<1, 128, 0, stream>>>(ds + 256, ds + 264, fdbng, fdbnb, fs + 256, fs + 264, 3, (double)NSAMP);
    // fg_bn1 stats (cnt 524288, 128ch)
    k_attn1_stats<<<2048, 128, 0, stream>>>(BUFQ, BUFK, xyz, knn, fdw1, fdb1, fs + 256, fs + 264,
                                            fdw2, fdb2, ds + 272, ds + 400);
    k_finalize<<<1, 128, 0, stream>>>(ds + 272, ds + 400, g1g, g1b, fs + 272, fs + 400, 128, (double)NSAMP);
    // fg_bn2 stats (cnt 524288, 16ch)
    k_attn2_stats<<<2048, 128, 0, stream>>>(BUFQ, BUFK, xyz, knn, fdw1, fdb1, fs + 256, fs + 264,
                                            fdw2, fdb2, fs + 272, fs + 400, fgw1, fgb1, ds + 528, ds + 544);
    k_finalize<<<1, 128, 0, stream>>>(ds + 528, ds + 544, g2g, g2b, fs + 528, fs + 544, 16, (double)NSAMP);
    // final attention -> res (BUF0), bn2 stats
    k_attn_final<<<2048, 128, 0, stream>>>(BUFQ, BUFK, BUFV, xyz, knn, fdw1, fdb1, fs + 256, fs + 264,
                                           fdw2, fdb2, fs + 272, fs + 400, fgw1, fgb1,
                                           fs + 528, fs + 544, fgw2, fgb2,
                                           BUF0, ds + 560, ds + 688);
    k_finalize<<<1, 128, 0, stream>>>(ds + 560, ds + 688, bn2g, bn2b, fs + 560, fs + 688, 128, (double)NPOINTS);
    // y3 = relu(bn2(res)) @ w3 -> BUFQ, bn3 stats
    k_gemm3<<<512, 512, 0, stream>>>(BUF0, fs + 560, fs + 688, w3, BUFQ, ds + 816, ds + 944);
    k_finalize<<<1, 128, 0, stream>>>(ds + 816, ds + 944, bn3g, bn3b, fs + 816, fs + 944, 128, (double)NPOINTS);
    // output
    float* outp = (float*)d_out;
    k_out<<<2048, 256, 0, stream>>>(BUFQ, fs + 816, fs + 944, feat, outp + 98304);
    k_copy_f32<<<192, 256, 0, stream>>>(xyz, outp, 98304);
}

// Round 4
// 614.733 us; speedup vs baseline: 2.8650x; 1.0861x over previous
//
#include <hip/hip_runtime.h>
#include <hip/hip_bf16.h>

constexpr int NPOINTS = 2 * 16384;        // B*N
constexpr int NSAMP   = NPOINTS * 16;     // B*N*K

typedef __attribute__((ext_vector_type(8))) short short8;
typedef __attribute__((ext_vector_type(4))) float f32x4;

__device__ inline unsigned short f2bf(float x) {
    __hip_bfloat16 h = __float2bfloat16(x);
    unsigned short u;
    __builtin_memcpy(&u, &h, 2);
    return u;
}
__device__ inline float bf2f(unsigned short u) {
    return __uint_as_float(((unsigned)u) << 16);
}

// ---------------------------------------------------------------- GEMM + bn stats
// y = X @ W (f32). 512 threads = 4 rows per barrier round. Per-channel stats.
__global__ __launch_bounds__(512) void k_gemm_bn1(
    const float* __restrict__ X, const float* __restrict__ W,
    float* __restrict__ Y, double* __restrict__ dsum, double* __restrict__ dsq)
{
    __shared__ float wl[128 * 128];
    __shared__ float xr[4][128];
    __shared__ double rd[512];
    const int tid = threadIdx.x;
    const int h = tid >> 7, c = tid & 127;
    for (int i = tid; i < 128 * 128; i += 512) wl[i] = W[i];
    __syncthreads();
    double ls = 0.0, lq = 0.0;
    const int r0 = blockIdx.x * 64;
    for (int r = r0; r < r0 + 64; r += 4) {
        xr[h][c] = X[(r + h) * 128 + c];
        __syncthreads();
        float acc = 0.f;
        #pragma unroll 8
        for (int j = 0; j < 128; ++j) acc = fmaf(xr[h][j], wl[j * 128 + c], acc);
        Y[(r + h) * 128 + c] = acc;
        ls += acc; lq += (double)acc * acc;
        __syncthreads();
    }
    rd[tid] = ls; __syncthreads();
    double ts = (h == 0) ? (rd[c] + rd[128 + c] + rd[256 + c] + rd[384 + c]) : 0.0;
    __syncthreads();
    rd[tid] = lq; __syncthreads();
    if (h == 0) {
        double tq = rd[c] + rd[128 + c] + rd[256 + c] + rd[384 + c];
        atomicAdd(&dsum[c], ts);
        atomicAdd(&dsq[c], tq);
    }
}

// finalize BN: scale = g*rsqrt(var+eps), shift = b - mean*scale
__global__ void k_finalize(const double* __restrict__ sum, const double* __restrict__ sq,
                           const float* __restrict__ g, const float* __restrict__ b,
                           float* __restrict__ scale, float* __restrict__ shift, int nch, double cnt)
{
    int c = threadIdx.x;
    if (c < nch) {
        double m = sum[c] / cnt;
        double v = sq[c] / cnt - m * m;
        double s = (double)g[c] / sqrt(v + 1e-5);
        scale[c] = (float)s;
        shift[c] = (float)((double)b[c] - m * s);
    }
}

// fused q/k/v: f = relu(bn1(Y)); q=f@Wq+bq (f32), k/v likewise -> bf16 tables.
// Weights bf16-pair-packed in LDS (32 KB each).
__global__ __launch_bounds__(512) void k_qkv(
    const float* __restrict__ Y, const float* __restrict__ sc, const float* __restrict__ sh,
    const float* __restrict__ Wq, const float* __restrict__ Bq,
    const float* __restrict__ Wk, const float* __restrict__ Bk,
    const float* __restrict__ Wv, const float* __restrict__ Bv,
    float* __restrict__ Qo, unsigned short* __restrict__ Ko, unsigned short* __restrict__ Vo)
{
    __shared__ unsigned int wq[64 * 128], wk[64 * 128], wv[64 * 128];  // 96 KB
    __shared__ float xr[4][128];
    const int tid = threadIdx.x;
    const int h = tid >> 7, c = tid & 127;
    for (int i = tid; i < 64 * 128; i += 512) {
        int jj = i >> 7, cc = i & 127;
        wq[i] = (unsigned)f2bf(Wq[(2 * jj) * 128 + cc]) | ((unsigned)f2bf(Wq[(2 * jj + 1) * 128 + cc]) << 16);
        wk[i] = (unsigned)f2bf(Wk[(2 * jj) * 128 + cc]) | ((unsigned)f2bf(Wk[(2 * jj + 1) * 128 + cc]) << 16);
        wv[i] = (unsigned)f2bf(Wv[(2 * jj) * 128 + cc]) | ((unsigned)f2bf(Wv[(2 * jj + 1) * 128 + cc]) << 16);
    }
    const float a = sc[c], b = sh[c];
    const float bq = Bq[c], bk = Bk[c], bv = Bv[c];
    __syncthreads();
    const int r0 = blockIdx.x * 64;
    for (int r = r0; r < r0 + 64; r += 4) {
        xr[h][c] = fmaxf(fmaf(a, Y[(r + h) * 128 + c], b), 0.f);
        __syncthreads();
        float aq = bq, ak = bk, av = bv;
        #pragma unroll 8
        for (int jj = 0; jj < 64; ++jj) {
            float f0 = xr[h][2 * jj], f1 = xr[h][2 * jj + 1];
            unsigned uq = wq[jj * 128 + c], uk = wk[jj * 128 + c], uv = wv[jj * 128 + c];
            aq = fmaf(f0, __uint_as_float(uq << 16), aq);
            aq = fmaf(f1, __uint_as_float(uq & 0xffff0000u), aq);
            ak = fmaf(f0, __uint_as_float(uk << 16), ak);
            ak = fmaf(f1, __uint_as_float(uk & 0xffff0000u), ak);
            av = fmaf(f0, __uint_as_float(uv << 16), av);
            av = fmaf(f1, __uint_as_float(uv & 0xffff0000u), av);
        }
        Qo[(r + h) * 128 + c] = aq;
        Ko[(r + h) * 128 + c] = f2bf(ak);
        Vo[(r + h) * 128 + c] = f2bf(av);
        __syncthreads();
    }
}

// stats of h = rel @ fd_w1 + fd_b1 over (B,N,K), 3 channels
__global__ __launch_bounds__(256) void k_fd_stats(
    const float* __restrict__ xyz, const int* __restrict__ knn,
    const float* __restrict__ fdw1, const float* __restrict__ fdb1,
    double* __restrict__ dsum, double* __restrict__ dsq)
{
    float wd[9], bd[3];
    #pragma unroll
    for (int i = 0; i < 9; ++i) wd[i] = fdw1[i];
    #pragma unroll
    for (int j = 0; j < 3; ++j) bd[j] = fdb1[j];
    double ls[3] = {0, 0, 0}, lq[3] = {0, 0, 0};
    for (int s = blockIdx.x * blockDim.x + threadIdx.x; s < NSAMP; s += gridDim.x * blockDim.x) {
        int p = s >> 4;
        int b = p >> 14, n = p & 16383;
        int idx = knn[s];
        const float* pa = xyz + (b * 16384 + n) * 3;
        const float* pb = xyz + (b * 16384 + idx) * 3;
        float r0 = pa[0] - pb[0], r1 = pa[1] - pb[1], r2 = pa[2] - pb[2];
        #pragma unroll
        for (int j = 0; j < 3; ++j) {
            float h = r0 * wd[j] + r1 * wd[3 + j] + r2 * wd[6 + j] + bd[j];
            ls[j] += h; lq[j] += (double)h * h;
        }
    }
    #pragma unroll
    for (int j = 0; j < 3; ++j) {
        double v = ls[j];
        for (int o = 32; o; o >>= 1) v += __shfl_down(v, o);
        if ((threadIdx.x & 63) == 0) atomicAdd(&dsum[j], v);
        v = lq[j];
        for (int o = 32; o; o >>= 1) v += __shfl_down(v, o);
        if ((threadIdx.x & 63) == 0) atomicAdd(&dsq[j], v);
    }
}

// stats of attn0 = q - k_gather + pos_enc over (B,N,K), 128 channels
__global__ __launch_bounds__(128) void k_attn1_stats(
    const float* __restrict__ Q, const unsigned short* __restrict__ Kb,
    const float* __restrict__ xyz, const int* __restrict__ knn,
    const float* __restrict__ fdw1, const float* __restrict__ fdb1,
    const float* __restrict__ fds, const float* __restrict__ fdh,
    const float* __restrict__ fdw2, const float* __restrict__ fdb2,
    double* __restrict__ dsum, double* __restrict__ dsq)
{
    __shared__ float pe3[16][3];
    __shared__ int idxs[16];
    const int tid = threadIdx.x;
    const float w0 = fdw2[tid], w1c = fdw2[128 + tid], w2c = fdw2[256 + tid], b2c = fdb2[tid];
    float wd[9], bd[3], fs3[3], fh3[3];
    #pragma unroll
    for (int i = 0; i < 9; ++i) wd[i] = fdw1[i];
    #pragma unroll
    for (int j = 0; j < 3; ++j) { bd[j] = fdb1[j]; fs3[j] = fds[j]; fh3[j] = fdh[j]; }
    double ls = 0.0, lq = 0.0;
    for (int p = blockIdx.x; p < NPOINTS; p += gridDim.x) {
        const int b = p >> 14;
        if (tid < 16) {
            const int idx = knn[p * 16 + tid];
            idxs[tid] = idx;
            const int n = p & 16383;
            const float* pa = xyz + (b * 16384 + n) * 3;
            const float* pb = xyz + (b * 16384 + idx) * 3;
            float r0 = pa[0] - pb[0], r1 = pa[1] - pb[1], r2 = pa[2] - pb[2];
            #pragma unroll
            for (int j = 0; j < 3; ++j) {
                float h = r0 * wd[j] + r1 * wd[3 + j] + r2 * wd[6 + j] + bd[j];
                pe3[tid][j] = fmaxf(fmaf(fs3[j], h, fh3[j]), 0.f);
            }
        }
        __syncthreads();
        const float qc = Q[p * 128 + tid];
        const unsigned short* kbase = Kb + (size_t)(b << 14) * 128;
        #pragma unroll
        for (int kk = 0; kk < 16; ++kk) {
            float kv = bf2f(kbase[idxs[kk] * 128 + tid]);
            float pec = fmaf(pe3[kk][0], w0, fmaf(pe3[kk][1], w1c, fmaf(pe3[kk][2], w2c, b2c)));
            float a0 = qc - kv + pec;
            ls += a0; lq += (double)a0 * a0;
        }
        __syncthreads();
    }
    atomicAdd(&dsum[tid], ls);
    atomicAdd(&dsq[tid], lq);
}

// stats of t = relu(bn(attn0)) @ fg_w1 + fg_b1 over (B,N,K), 16 channels.
// 1 wave/block; stage1 via mfma_f32_16x16x32_bf16 on swizzled bf16 s1 tile.
__global__ __launch_bounds__(64) void k_attn2_stats(
    const float* __restrict__ Q, const unsigned short* __restrict__ Kb,
    const float* __restrict__ xyz, const int* __restrict__ knn,
    const float* __restrict__ fdw1, const float* __restrict__ fdb1,
    const float* __restrict__ fds, const float* __restrict__ fdh,
    const float* __restrict__ fdw2, const float* __restrict__ fdb2,
    const float* __restrict__ g1s, const float* __restrict__ g1h,
    const float* __restrict__ fgw1, const float* __restrict__ fgb1,
    double* __restrict__ dsum, double* __restrict__ dsq)
{
    __shared__ unsigned short s1b[2048];   // [16 kk][128 c] bf16, XOR-swizzled
    __shared__ float pe3[16][3];
    __shared__ int idxs[16];
    __shared__ double rd[64];
    const int tid = threadIdx.x;
    const int c0 = tid, c1 = tid + 64;
    const int a16 = tid & 15, g8 = (tid >> 4) * 8;
    const float w0a = fdw2[c0], w1a = fdw2[128 + c0], w2a = fdw2[256 + c0], bba = fdb2[c0];
    const float w0b = fdw2[c1], w1b = fdw2[128 + c1], w2b = fdw2[256 + c1], bbb = fdb2[c1];
    const float sA = g1s[c0], hA = g1h[c0], sB = g1s[c1], hB = g1h[c1];
    const float tb = fgb1[a16];
    float wd[9], bd[3], fs3[3], fh3[3];
    #pragma unroll
    for (int i = 0; i < 9; ++i) wd[i] = fdw1[i];
    #pragma unroll
    for (int j = 0; j < 3; ++j) { bd[j] = fdb1[j]; fs3[j] = fds[j]; fh3[j] = fdh[j]; }
    short8 bfrag[4];
    #pragma unroll
    for (int s = 0; s < 4; ++s)
        #pragma unroll
        for (int i = 0; i < 8; ++i)
            bfrag[s][i] = (short)f2bf(fgw1[(32 * s + g8 + i) * 16 + a16]);
    double ls = 0.0, lq = 0.0;
    for (int p = blockIdx.x; p < NPOINTS; p += gridDim.x) {
        const int b = p >> 14;
        if (tid < 16) {
            const int idx = knn[p * 16 + tid];
            idxs[tid] = idx;
            const int n = p & 16383;
            const float* pa = xyz + (b * 16384 + n) * 3;
            const float* pb = xyz + (b * 16384 + idx) * 3;
            #pragma unroll
            for (int j = 0; j < 3; ++j) {
                float h = (pa[0] - pb[0]) * wd[j] + (pa[1] - pb[1]) * wd[3 + j] + (pa[2] - pb[2]) * wd[6 + j] + bd[j];
                pe3[tid][j] = fmaxf(fmaf(fs3[j], h, fh3[j]), 0.f);
            }
        }
        __syncthreads();
        const float qa = Q[p * 128 + c0], qb = Q[p * 128 + c1];
        const unsigned short* kbase = Kb + (size_t)(b << 14) * 128;
        #pragma unroll
        for (int kk = 0; kk < 16; ++kk) {
            const unsigned short* krow = kbase + idxs[kk] * 128;
            float pea = fmaf(pe3[kk][0], w0a, fmaf(pe3[kk][1], w1a, fmaf(pe3[kk][2], w2a, bba)));
            float peb = fmaf(pe3[kk][0], w0b, fmaf(pe3[kk][1], w1b, fmaf(pe3[kk][2], w2b, bbb)));
            float a0 = qa - bf2f(krow[c0]) + pea;
            float a1 = qb - bf2f(krow[c1]) + peb;
            const int sw = (kk & 7) << 3;
            s1b[(kk * 128 + c0) ^ sw] = f2bf(fmaxf(fmaf(sA, a0, hA), 0.f));
            s1b[(kk * 128 + c1) ^ sw] = f2bf(fmaxf(fmaf(sB, a1, hB), 0.f));
        }
        __syncthreads();
        f32x4 acc = {0.f, 0.f, 0.f, 0.f};
        #pragma unroll
        for (int s = 0; s < 4; ++s) {
            int idx = (a16 * 128 + s * 32 + g8) ^ ((a16 & 7) << 3);
            short8 af = *reinterpret_cast<const short8*>(&s1b[idx]);
            acc = __builtin_amdgcn_mfma_f32_16x16x32_bf16(af, bfrag[s], acc, 0, 0, 0);
        }
        #pragma unroll
        for (int r = 0; r < 4; ++r) {
            float t = acc[r] + tb;
            ls += t; lq += (double)t * t;
        }
        __syncthreads();
    }
    rd[tid] = ls; __syncthreads();
    double ts = (tid < 16) ? (rd[tid] + rd[tid + 16] + rd[tid + 32] + rd[tid + 48]) : 0.0;
    __syncthreads();
    rd[tid] = lq; __syncthreads();
    if (tid < 16) {
        double tq = rd[tid] + rd[tid + 16] + rd[tid + 32] + rd[tid + 48];
        atomicAdd(&dsum[tid], ts);
        atomicAdd(&dsq[tid], tq);
    }
}

// full attention: stage1 (mfma) -> bn -> stage2 -> softmax -> PV ; bn2 stats.
__global__ __launch_bounds__(64) void k_attn_final(
    const float* __restrict__ Q, const unsigned short* __restrict__ Kb, const unsigned short* __restrict__ Vb,
    const float* __restrict__ xyz, const int* __restrict__ knn,
    const float* __restrict__ fdw1, const float* __restrict__ fdb1,
    const float* __restrict__ fds, const float* __restrict__ fdh,
    const float* __restrict__ fdw2, const float* __restrict__ fdb2,
    const float* __restrict__ g1s, const float* __restrict__ g1h,
    const float* __restrict__ fgw1, const float* __restrict__ fgb1,
    const float* __restrict__ g2s, const float* __restrict__ g2h,
    const float* __restrict__ fgw2, const float* __restrict__ fgb2,
    float* __restrict__ Res, double* __restrict__ dsum, double* __restrict__ dsq)
{
    __shared__ unsigned short s1b[2048];
    __shared__ float t2l[16 * 17];
    __shared__ float wl[16 * 17];
    __shared__ float pe3[16][3];
    __shared__ int idxs[16];
    const int tid = threadIdx.x;
    const int c0 = tid, c1 = tid + 64;
    const int a16 = tid & 15, g4 = tid >> 4, g8 = g4 * 8;
    const float w0a = fdw2[c0], w1a = fdw2[128 + c0], w2a = fdw2[256 + c0], bba = fdb2[c0];
    const float w0b = fdw2[c1], w1b = fdw2[128 + c1], w2b = fdw2[256 + c1], bbb = fdb2[c1];
    const float sA = g1s[c0], hA = g1h[c0], sB = g1s[c1], hB = g1h[c1];
    const float tb = fgb1[a16];
    const float s2a = g2s[a16], s2h = g2h[a16], b2a = fgb2[a16];
    float wd[9], bd[3], fs3[3], fh3[3];
    #pragma unroll
    for (int i = 0; i < 9; ++i) wd[i] = fdw1[i];
    #pragma unroll
    for (int j = 0; j < 3; ++j) { bd[j] = fdb1[j]; fs3[j] = fds[j]; fh3[j] = fdh[j]; }
    short8 bfrag[4];
    #pragma unroll
    for (int s = 0; s < 4; ++s)
        #pragma unroll
        for (int i = 0; i < 8; ++i)
            bfrag[s][i] = (short)f2bf(fgw1[(32 * s + g8 + i) * 16 + a16]);
    float wv2[16];
    #pragma unroll
    for (int j = 0; j < 16; ++j) wv2[j] = fgw2[j * 16 + a16];
    double lsA = 0.0, lqA = 0.0, lsB = 0.0, lqB = 0.0;
    for (int p = blockIdx.x; p < NPOINTS; p += gridDim.x) {
        const int b = p >> 14;
        if (tid < 16) {
            const int idx = knn[p * 16 + tid];
            idxs[tid] = idx;
            const int n = p & 16383;
            const float* pa = xyz + (b * 16384 + n) * 3;
            const float* pb = xyz + (b * 16384 + idx) * 3;
            #pragma unroll
            for (int j = 0; j < 3; ++j) {
                float h = (pa[0] - pb[0]) * wd[j] + (pa[1] - pb[1]) * wd[3 + j] + (pa[2] - pb[2]) * wd[6 + j] + bd[j];
                pe3[tid][j] = fmaxf(fmaf(fs3[j], h, fh3[j]), 0.f);
            }
        }
        __syncthreads();
        const float qa = Q[p * 128 + c0], qb = Q[p * 128 + c1];
        const unsigned short* kbase = Kb + (size_t)(b << 14) * 128;
        #pragma unroll
        for (int kk = 0; kk < 16; ++kk) {
            const unsigned short* krow = kbase + idxs[kk] * 128;
            float pea = fmaf(pe3[kk][0], w0a, fmaf(pe3[kk][1], w1a, fmaf(pe3[kk][2], w2a, bba)));
            float peb = fmaf(pe3[kk][0], w0b, fmaf(pe3[kk][1], w1b, fmaf(pe3[kk][2], w2b, bbb)));
            float a0 = qa - bf2f(krow[c0]) + pea;
            float a1 = qb - bf2f(krow[c1]) + peb;
            const int sw = (kk & 7) << 3;
            s1b[(kk * 128 + c0) ^ sw] = f2bf(fmaxf(fmaf(sA, a0, hA), 0.f));
            s1b[(kk * 128 + c1) ^ sw] = f2bf(fmaxf(fmaf(sB, a1, hB), 0.f));
        }
        __syncthreads();
        f32x4 acc = {0.f, 0.f, 0.f, 0.f};
        #pragma unroll
        for (int s = 0; s < 4; ++s) {
            int idx = (a16 * 128 + s * 32 + g8) ^ ((a16 & 7) << 3);
            short8 af = *reinterpret_cast<const short8*>(&s1b[idx]);
            acc = __builtin_amdgcn_mfma_f32_16x16x32_bf16(af, bfrag[s], acc, 0, 0, 0);
        }
        // t2 = relu(bn2(t)); lane holds t[kk=g4*4+r][a=a16]
        #pragma unroll
        for (int r = 0; r < 4; ++r)
            t2l[(g4 * 4 + r) * 17 + a16] = fmaxf(fmaf(s2a, acc[r] + tb, s2h), 0.f);
        __syncthreads();
        // stage2: u[kk][a'] for kk in my group, a' = a16
        float ur[4];
        #pragma unroll
        for (int r = 0; r < 4; ++r) {
            float u = b2a;
            #pragma unroll
            for (int j = 0; j < 16; ++j) u = fmaf(t2l[(g4 * 4 + r) * 17 + j], wv2[j], u);
            ur[r] = u;
        }
        // softmax over kk per column a16 (across the 4 lane-groups)
        float m = fmaxf(fmaxf(ur[0], ur[1]), fmaxf(ur[2], ur[3]));
        m = fmaxf(m, __shfl_xor(m, 16));
        m = fmaxf(m, __shfl_xor(m, 32));
        float e[4], ssum = 0.f;
        #pragma unroll
        for (int r = 0; r < 4; ++r) { e[r] = __expf(ur[r] - m); ssum += e[r]; }
        ssum += __shfl_xor(ssum, 16);
        ssum += __shfl_xor(ssum, 32);
        float inv = 1.f / ssum;
        #pragma unroll
        for (int r = 0; r < 4; ++r) wl[(g4 * 4 + r) * 17 + a16] = e[r] * inv;
        __syncthreads();
        // PV: res[c] = sum_k (V[idx_k][c] + pe[k][c]) * w[k][c&15]
        const unsigned short* vbase = Vb + (size_t)(b << 14) * 128;
        float rc0 = 0.f, rc1 = 0.f;
        #pragma unroll
        for (int kk = 0; kk < 16; ++kk) {
            const unsigned short* vrow = vbase + idxs[kk] * 128;
            float wgt = wl[kk * 17 + a16];
            float pea = fmaf(pe3[kk][0], w0a, fmaf(pe3[kk][1], w1a, fmaf(pe3[kk][2], w2a, bba)));
            float peb = fmaf(pe3[kk][0], w0b, fmaf(pe3[kk][1], w1b, fmaf(pe3[kk][2], w2b, bbb)));
            rc0 = fmaf(bf2f(vrow[c0]) + pea, wgt, rc0);
            rc1 = fmaf(bf2f(vrow[c1]) + peb, wgt, rc1);
        }
        Res[p * 128 + c0] = rc0;
        Res[p * 128 + c1] = rc1;
        lsA += rc0; lqA += (double)rc0 * rc0;
        lsB += rc1; lqB += (double)rc1 * rc1;
        __syncthreads();
    }
    atomicAdd(&dsum[c0], lsA); atomicAdd(&dsq[c0], lqA);
    atomicAdd(&dsum[c1], lsB); atomicAdd(&dsq[c1], lqB);
}

// y3 = relu(bn2(res)) @ w3 ; bn3 stats
__global__ __launch_bounds__(512) void k_gemm3(
    const float* __restrict__ Rin, const float* __restrict__ sc, const float* __restrict__ sh,
    const float* __restrict__ W3, float* __restrict__ Y3,
    double* __restrict__ dsum, double* __restrict__ dsq)
{
    __shared__ float wl[128 * 128];
    __shared__ float xr[4][128];
    __shared__ double rd[512];
    const int tid = threadIdx.x;
    const int h = tid >> 7, c = tid & 127;
    for (int i = tid; i < 128 * 128; i += 512) wl[i] = W3[i];
    const float a = sc[c], b = sh[c];
    __syncthreads();
    double ls = 0.0, lq = 0.0;
    const int r0 = blockIdx.x * 64;
    for (int r = r0; r < r0 + 64; r += 4) {
        xr[h][c] = fmaxf(fmaf(a, Rin[(r + h) * 128 + c], b), 0.f);
        __syncthreads();
        float acc = 0.f;
        #pragma unroll 8
        for (int j = 0; j < 128; ++j) acc = fmaf(xr[h][j], wl[j * 128 + c], acc);
        Y3[(r + h) * 128 + c] = acc;
        ls += acc; lq += (double)acc * acc;
        __syncthreads();
    }
    rd[tid] = ls; __syncthreads();
    double ts = (h == 0) ? (rd[c] + rd[128 + c] + rd[256 + c] + rd[384 + c]) : 0.0;
    __syncthreads();
    rd[tid] = lq; __syncthreads();
    if (h == 0) {
        double tq = rd[c] + rd[128 + c] + rd[256 + c] + rd[384 + c];
        atomicAdd(&dsum[c], ts);
        atomicAdd(&dsq[c], tq);
    }
}

// out = relu(bn3(y3) + identity)
__global__ void k_out(const float* __restrict__ Y3, const float* __restrict__ sc,
                      const float* __restrict__ sh, const float* __restrict__ feat,
                      float* __restrict__ out)
{
    const int total = NPOINTS * 128;
    for (int i = blockIdx.x * blockDim.x + threadIdx.x; i < total; i += gridDim.x * blockDim.x) {
        int c = i & 127;
        float v = fmaf(sc[c], Y3[i], sh[c]) + feat[i];
        out[i] = fmaxf(v, 0.f);
    }
}

__global__ void k_copy_f32(const float* __restrict__ s, float* __restrict__ d, int n)
{
    for (int i = blockIdx.x * blockDim.x + threadIdx.x; i < n; i += gridDim.x * blockDim.x) d[i] = s[i];
}

extern "C" void kernel_launch(void* const* d_in, const int* in_sizes, int n_in,
                              void* d_out, int out_size, void* d_ws, size_t ws_size,
                              hipStream_t stream)
{
    (void)in_sizes; (void)n_in; (void)out_size; (void)ws_size;
    const float* xyz   = (const float*)d_in[0];
    const float* feat  = (const float*)d_in[1];
    const int*   knn   = (const int*)d_in[2];
    const float* w1    = (const float*)d_in[3];
    const float* bn1g  = (const float*)d_in[4];
    const float* bn1b  = (const float*)d_in[5];
    const float* lqw   = (const float*)d_in[6];
    const float* lqb   = (const float*)d_in[7];
    const float* lkw   = (const float*)d_in[8];
    const float* lkb   = (const float*)d_in[9];
    const float* lvw   = (const float*)d_in[10];
    const float* lvb   = (const float*)d_in[11];
    const float* fdw1  = (const float*)d_in[12];
    const float* fdb1  = (const float*)d_in[13];
    const float* fdbng = (const float*)d_in[14];
    const float* fdbnb = (const float*)d_in[15];
    const float* fdw2  = (const float*)d_in[16];
    const float* fdb2  = (const float*)d_in[17];
    const float* g1g   = (const float*)d_in[18];
    const float* g1b   = (const float*)d_in[19];
    const float* fgw1  = (const float*)d_in[20];
    const float* fgb1  = (const float*)d_in[21];
    const float* g2g   = (const float*)d_in[22];
    const float* g2b   = (const float*)d_in[23];
    const float* fgw2  = (const float*)d_in[24];
    const float* fgb2  = (const float*)d_in[25];
    const float* bn2g  = (const float*)d_in[26];
    const float* bn2b  = (const float*)d_in[27];
    const float* w3    = (const float*)d_in[28];
    const float* bn3g  = (const float*)d_in[29];
    const float* bn3b  = (const float*)d_in[30];

    float* wsf  = (float*)d_ws;
    float* BUF0 = wsf;                                     // y, later res (16 MB)
    float* BUFQ = wsf + 4194304;                           // q, later y3 (16 MB)
    unsigned short* BUFK = (unsigned short*)(wsf + 2 * 4194304);   // bf16 k (8 MB)
    unsigned short* BUFV = BUFK + 4194304;                 // bf16 v (8 MB)
    double* ds  = (double*)(wsf + 3 * 4194304);
    float*  fs  = (float*)(ds + 1072);

    hipMemsetAsync(ds, 0, 1072 * sizeof(double), stream);

    // bn1 over feat@w1 (cnt 32768, 128ch)
    k_gemm_bn1<<<512, 512, 0, stream>>>(feat, w1, BUF0, ds + 0, ds + 128);
    k_finalize<<<1, 128, 0, stream>>>(ds + 0, ds + 128, bn1g, bn1b, fs + 0, fs + 128, 128, (double)NPOINTS);
    // fused q,k,v projections
    k_qkv<<<512, 512, 0, stream>>>(BUF0, fs + 0, fs + 128, lqw, lqb, lkw, lkb, lvw, lvb, BUFQ, BUFK, BUFV);
    // fd BN stats (cnt 524288, 3ch)
    k_fd_stats<<<256, 256, 0, stream>>>(xyz, knn, fdw1, fdb1, ds + 256, ds + 264);
    k_finalize<<<1, 128, 0, stream>>>(ds + 256, ds + 264, fdbng, fdbnb, fs + 256, fs + 264, 3, (double)NSAMP);
    // fg_bn1 stats (cnt 524288, 128ch)
    k_attn1_stats<<<4096, 128, 0, stream>>>(BUFQ, BUFK, xyz, knn, fdw1, fdb1, fs + 256, fs + 264,
                                            fdw2, fdb2, ds + 272, ds + 400);
    k_finalize<<<1, 128, 0, stream>>>(ds + 272, ds + 400, g1g, g1b, fs + 272, fs + 400, 128, (double)NSAMP);
    // fg_bn2 stats (cnt 524288, 16ch)
    k_attn2_stats<<<4096, 64, 0, stream>>>(BUFQ, BUFK, xyz, knn, fdw1, fdb1, fs + 256, fs + 264,
                                           fdw2, fdb2, fs + 272, fs + 400, fgw1, fgb1, ds + 528, ds + 544);
    k_finalize<<<1, 128, 0, stream>>>(ds + 528, ds + 544, g2g, g2b, fs + 528, fs + 544, 16, (double)NSAMP);
    // final attention -> res (BUF0), bn2 stats
    k_attn_final<<<4096, 64, 0, stream>>>(BUFQ, BUFK, BUFV, xyz, knn, fdw1, fdb1, fs + 256, fs + 264,
                                          fdw2, fdb2, fs + 272, fs + 400, fgw1, fgb1,
                                          fs + 528, fs + 544, fgw2, fgb2,
                                          BUF0, ds + 560, ds + 688);
    k_finalize<<<1, 128, 0, stream>>>(ds + 560, ds + 688, bn2g, bn2b, fs + 560, fs + 688, 128, (double)NPOINTS);
    // y3 = relu(bn2(res)) @ w3 -> BUFQ, bn3 stats
    k_gemm3<<<512, 512, 0, stream>>>(BUF0, fs + 560, fs + 688, w3, BUFQ, ds + 816, ds + 944);
    k_finalize<<<1, 128, 0, stream>>>(ds + 816, ds + 944, bn3g, bn3b, fs + 816, fs + 944, 128, (double)NPOINTS);
    // output
    float* outp = (float*)d_out;
    k_out<<<2048, 256, 0, stream>>>(BUFQ, fs + 816, fs + 944, feat, outp + 98304);
    k_copy_f32<<<192, 256, 0, stream>>>(xyz, outp, 98304);
}